// Round 1
// 169.637 us; speedup vs baseline: 1.3020x; 1.3020x over previous
//
#include <hip/hip_runtime.h>
#include <math.h>

// DigitCaps dynamic routing, MFMA version.
// u[b,n,cl] = sum_j x[b,n,j] W[n,j,cl] computed per-n on matrix cores:
//   v_mfma_f32_16x16x16f16, M=16 (cl tile = one capsule c), N=16 (batch), K=16
//   (j=8 real, lanes 32-63 of A/B fragments zeroed so k=8..15 contribute 0).
// No LDS anywhere: W fragments are 256B-contiguous wave reads from a packed
// Wt[n][cl][j] f16 buffer; x fragments are per-lane 8B reads from xh[b][n][j]
// f16 with full L1 cache-line reuse across 8 consecutive n.
// Routing (t = u.v, softmax over c, s += w*u) stays in registers on the MFMA
// D-layout: lane holds (b = lane&15, l = 4*(lane>>4)+reg) -> t needs 4 fma +
// 2 shfl_xor per capsule; softmax fully in-lane.
// Pass 0 (uniform coupling): accumulate u straight into the MFMA C operand.

namespace {
constexpr int B_   = 128;
constexpr int N_   = 4608;
constexpr int C_   = 10;
constexpr int L_   = 16;
constexpr int CL   = C_ * L_;            // 160
constexpr int NCHK = 256;                // partial chunks (grid.x)
constexpr int TILE_N = N_ / NCHK;        // 18 n per block
constexpr int BCL  = B_ * CL;            // 20480
constexpr int RED_G = 16;
constexpr int RED_K = NCHK / RED_G;      // 16
constexpr int WBLK = (N_ * CL) / 256;    // 2880 blocks: W pack
constexpr int XBLK = (B_ * N_) / 256;    // 2304 blocks: x convert
}

typedef _Float16 v4h __attribute__((ext_vector_type(4)));
typedef _Float16 v8h __attribute__((ext_vector_type(8)));
typedef float    v4f __attribute__((ext_vector_type(4)));

// W [N][8][160] f32 -> Wt [N][160][8] f16 (transpose j<->cl, pack)
// x [B][N][8]  f32 -> xh [B][N][8]  f16 (straight convert)
__global__ __launch_bounds__(256)
void conv_pack(const float* __restrict__ W, const float* __restrict__ x,
               v8h* __restrict__ Wt, v8h* __restrict__ xh)
{
  if ((int)blockIdx.x < WBLK) {
    const int t  = blockIdx.x * 256 + threadIdx.x;     // (n, cl)
    const int n  = t / CL, cl = t % CL;
    const float* p = W + (size_t)n * (8 * CL) + cl;
    v8h o;
#pragma unroll
    for (int j = 0; j < 8; ++j) o[j] = (_Float16)p[j * CL];
    Wt[t] = o;
  } else {
    const int t = ((int)blockIdx.x - WBLK) * 256 + threadIdx.x; // 8-float chunk
    const float4 a = ((const float4*)x)[(size_t)t * 2 + 0];
    const float4 b = ((const float4*)x)[(size_t)t * 2 + 1];
    v8h o = { (_Float16)a.x, (_Float16)a.y, (_Float16)a.z, (_Float16)a.w,
              (_Float16)b.x, (_Float16)b.y, (_Float16)b.z, (_Float16)b.w };
    xh[t] = o;
  }
}

// MODE 0: uniform coupling (1/10 folded into reduce_b scale)
// MODE 1: logits t = u.v0      MODE 2: logits t = u.(v0+v1)
template<int MODE>
__global__ __launch_bounds__(256, 2)
void pass_kernel(const _Float16* __restrict__ xh,
                 const _Float16* __restrict__ Wt,
                 const float* __restrict__ va,
                 const float* __restrict__ vb,
                 float* __restrict__ partials)      // [NCHK][B][C][L]
{
  const int lane = threadIdx.x & 63;
  const int wid  = threadIdx.x >> 6;     // 4 waves = 4 batch tiles of 16
  const int bl   = lane & 15;            // batch within tile (D col) / cl row (A)
  const int hi   = lane >> 4;            // 0..3: l-quarter in D rows
  const int b    = blockIdx.y * 64 + wid * 16 + bl;
  const int n0   = blockIdx.x * TILE_N;
  const bool lo  = lane < 32;            // lanes holding real K (j=0..7)
  const int kh   = (lane >> 4) & 1;      // k half for fragment loads

  v4f vv[C_];                            // v[b][c][4*hi .. 4*hi+3]
  if (MODE >= 1) {
#pragma unroll
    for (int c = 0; c < C_; ++c) {
      vv[c] = *(const v4f*)(va + ((size_t)b * C_ + c) * L_ + hi * 4);
      if (MODE == 2)
        vv[c] += *(const v4f*)(vb + ((size_t)b * C_ + c) * L_ + hi * 4);
    }
  }

  const v4f zf = {0.f, 0.f, 0.f, 0.f};
  v4f sacc[C_];
#pragma unroll
  for (int c = 0; c < C_; ++c) sacc[c] = zf;

  // per-lane fragment pointers (valid for lanes < 32; others stay zero)
  const _Float16* xp = xh + ((size_t)b * N_ + n0) * 8 + kh * 4;
  const _Float16* wp = Wt + ((size_t)n0 * CL + bl) * 8 + kh * 4;

  v4h xf = {};
  v4h wf[C_];
#pragma unroll
  for (int c = 0; c < C_; ++c) wf[c] = xf;

  for (int nn = 0; nn < TILE_N; ++nn) {
    if (lo) {
      xf = *(const v4h*)(xp + nn * 8);
#pragma unroll
      for (int c = 0; c < C_; ++c)
        wf[c] = *(const v4h*)(wp + (size_t)nn * (CL * 8) + c * (16 * 8));
    }

    if (MODE == 0) {
#pragma unroll
      for (int c = 0; c < C_; ++c)
        sacc[c] = __builtin_amdgcn_mfma_f32_16x16x16f16(wf[c], xf, sacc[c], 0, 0, 0);
    } else {
      v4f u[C_];
#pragma unroll
      for (int c = 0; c < C_; ++c)
        u[c] = __builtin_amdgcn_mfma_f32_16x16x16f16(wf[c], xf, zf, 0, 0, 0);

      // t[b,c] partial over this lane's 4 l's, then reduce across hi groups
      float tt[C_];
#pragma unroll
      for (int c = 0; c < C_; ++c) {
        float t = u[c][0] * vv[c][0];
        t = fmaf(u[c][1], vv[c][1], t);
        t = fmaf(u[c][2], vv[c][2], t);
        t = fmaf(u[c][3], vv[c][3], t);
        tt[c] = t;
      }
#pragma unroll
      for (int c = 0; c < C_; ++c) {
        tt[c] += __shfl_xor(tt[c], 16);
        tt[c] += __shfl_xor(tt[c], 32);
      }
      float es = 0.f;
#pragma unroll
      for (int c = 0; c < C_; ++c) { tt[c] = __expf(tt[c]); es += tt[c]; }
      const float rs = __builtin_amdgcn_rcpf(es);
#pragma unroll
      for (int c = 0; c < C_; ++c) {
        const float w = tt[c] * rs;
#pragma unroll
        for (int i = 0; i < 4; ++i)
          sacc[c][i] = fmaf(w, u[c][i], sacc[c][i]);
      }
    }
  }

  // lane writes (b, c, l = 4*hi..4*hi+3) as float4
  float* pout = partials + ((size_t)blockIdx.x * B_ + b) * CL + hi * 4;
#pragma unroll
  for (int c = 0; c < C_; ++c)
    *(v4f*)(pout + c * L_) = sacc[c];
}

// Stage A: sum 256 chunks down to 16 groups (fully coalesced streaming)
__global__ __launch_bounds__(256)
void reduce_a(const float* __restrict__ p, float* __restrict__ p2) {
  const int t   = blockIdx.x * 256 + threadIdx.x;   // 0 .. 16*BCL-1
  const int idx = t % BCL;
  const int g   = t / BCL;
  float a = 0.f;
#pragma unroll
  for (int k = 0; k < RED_K; ++k)
    a += p[(size_t)(g * RED_K + k) * BCL + idx];
  p2[t] = a;
}

// Stage B: sum 16 groups, add bias, squash (16-lane shuffle for ||s||^2)
__global__ __launch_bounds__(256)
void reduce_b(const float* __restrict__ p2, const float* __restrict__ biases,
              float* __restrict__ vout, float scale) {
  const int idx = blockIdx.x * 256 + threadIdx.x;   // 0 .. BCL-1
  float a = 0.f;
#pragma unroll
  for (int g = 0; g < RED_G; ++g) a += p2[(size_t)g * BCL + idx];
  const float s = a * scale + biases[idx % CL];
  float n2 = s * s;
#pragma unroll
  for (int o = 8; o; o >>= 1) n2 += __shfl_xor(n2, o, 16);
  const float n = sqrtf(n2);
  const float f = n2 / ((1.f + n2) * (n + 1e-7f));
  vout[idx] = f * s;
}

extern "C" void kernel_launch(void* const* d_in, const int* in_sizes, int n_in,
                              void* d_out, int out_size, void* d_ws, size_t ws_size,
                              hipStream_t stream) {
  const float* x      = (const float*)d_in[0];
  const float* W      = (const float*)d_in[1];
  const float* biases = (const float*)d_in[2];
  float* out = (float*)d_out;

  _Float16* Wt  = (_Float16*)d_ws;                       // 11.8 MB
  _Float16* xhp = Wt + (size_t)N_ * CL * 8;              //  9.4 MB
  float* partials = (float*)(xhp + (size_t)B_ * N_ * 8); // 21.0 MB
  float* p2 = partials + (size_t)NCHK * BCL;             //  1.3 MB
  float* v0 = p2 + (size_t)RED_G * BCL;
  float* v1 = v0 + BCL;

  conv_pack<<<WBLK + XBLK, 256, 0, stream>>>(W, x, (v8h*)Wt, (v8h*)xhp);

  const dim3 pg(NCHK, 2), pb(256);

  pass_kernel<0><<<pg, pb, 0, stream>>>(xhp, Wt, nullptr, nullptr, partials);
  reduce_a<<<(RED_G * BCL) / 256, 256, 0, stream>>>(partials, p2);
  reduce_b<<<BCL / 256, 256, 0, stream>>>(p2, biases, v0, 0.1f);

  pass_kernel<1><<<pg, pb, 0, stream>>>(xhp, Wt, v0, nullptr, partials);
  reduce_a<<<(RED_G * BCL) / 256, 256, 0, stream>>>(partials, p2);
  reduce_b<<<BCL / 256, 256, 0, stream>>>(p2, biases, v1, 1.0f);

  pass_kernel<2><<<pg, pb, 0, stream>>>(xhp, Wt, v0, v1, partials);
  reduce_a<<<(RED_G * BCL) / 256, 256, 0, stream>>>(partials, p2);
  reduce_b<<<BCL / 256, 256, 0, stream>>>(p2, biases, out, 1.0f);
}